// Round 4
// baseline (113.860 us; speedup 1.0000x reference)
//
#include <hip/hip_runtime.h>
#include <math.h>

// riemannian_exp: out[b] = key_poses[argmax(ybin[b])] @ Rodrigues(yres[b])
// B = 1048576, C = 100. Split design:
//   K1: pure streaming argmax of ybin (419 MB read, 1 MB u8 index write)
//   K2: gather + Rodrigues + 3x3 matmul (~51 MB traffic).

#define ROWS_PER_BLOCK 256

typedef float fvec4 __attribute__((ext_vector_type(4)));

// ---------------- Kernel 1: streaming argmax, 4 lanes per row ----------------
__global__ __launch_bounds__(256) void argmax100_kernel(
    const float* __restrict__ ybin,       // [B, 100]
    unsigned char* __restrict__ idx,      // [B]
    int B)
{
    const int tid = threadIdx.x;
    const int lane4 = tid & 3;
    const long long row = (long long)blockIdx.x * 64 + (tid >> 2);
    if (row >= B) return;

    const fvec4* rbase = reinterpret_cast<const fvec4*>(ybin + row * 100);
    float best = -INFINITY;
    int bi = 0;
    #pragma unroll
    for (int j = 0; j < 7; ++j) {
        int c = lane4 + j * 4;
        if (c < 25) {
            fvec4 v = __builtin_nontemporal_load(&rbase[c]);
            int i0 = c * 4;
            if (v.x > best) { best = v.x; bi = i0;     }
            if (v.y > best) { best = v.y; bi = i0 + 1; }
            if (v.z > best) { best = v.z; bi = i0 + 2; }
            if (v.w > best) { best = v.w; bi = i0 + 3; }
        }
    }
    #pragma unroll
    for (int m = 1; m <= 2; m <<= 1) {
        float ob = __shfl_xor(best, m);
        int   oi = __shfl_xor(bi, m);
        if (ob > best || (ob == best && oi < bi)) { best = ob; bi = oi; }
    }
    if (lane4 == 0) idx[row] = (unsigned char)bi;
}

// ---------------- Kernel 2: gather + Rodrigues + matmul ----------------
__global__ __launch_bounds__(256) void apply_kernel(
    const unsigned char* __restrict__ idx,  // [B]
    const float* __restrict__ yres,         // [B, 3]
    const float* __restrict__ key_poses,    // [100, 3, 3]
    float* __restrict__ out)                // [B, 3, 3]
{
    __shared__ float kp[912];
    __shared__ float s_yres[768];
    __shared__ unsigned char s_idx[256];
    __shared__ float s_out[2304];

    const int tid = threadIdx.x;
    const long long row0 = (long long)blockIdx.x * ROWS_PER_BLOCK;

    for (int i = tid; i < 900; i += 256) kp[i] = key_poses[i];
    {
        const float4* src = reinterpret_cast<const float4*>(yres + row0 * 3);
        float4* dst = reinterpret_cast<float4*>(s_yres);
        if (tid < 192) dst[tid] = src[tid];
        if (tid >= 192 && tid < 256) {
            reinterpret_cast<uchar4*>(s_idx)[tid - 192] =
                reinterpret_cast<const uchar4*>(idx + row0)[tid - 192];
        }
    }
    __syncthreads();

    {
        int bi = s_idx[tid];
        float rx = s_yres[tid * 3 + 0];
        float ry = s_yres[tid * 3 + 1];
        float rz = s_yres[tid * 3 + 2];
        float angle = sqrtf(rx * rx + ry * ry + rz * rz);
        float inv = 1.0f / fmaxf(angle, 1e-12f);
        float ax = rx * inv, ay = ry * inv, az = rz * inv;
        float s, cosv;
        __sincosf(angle, &s, &cosv);
        float c = 1.0f - cosv;

        float axx = ax * ax, ayy = ay * ay, azz = az * az;
        float axy = ax * ay, axz = ax * az, ayz = ay * az;

        float R00 = 1.0f + c * (-ayy - azz);
        float R01 = -s * az + c * axy;
        float R02 =  s * ay + c * axz;
        float R10 =  s * az + c * axy;
        float R11 = 1.0f + c * (-axx - azz);
        float R12 = -s * ax + c * ayz;
        float R20 = -s * ay + c * axz;
        float R21 =  s * ax + c * ayz;
        float R22 = 1.0f + c * (-axx - ayy);

        const float* P = &kp[bi * 9];
        float P00 = P[0], P01 = P[1], P02 = P[2];
        float P10 = P[3], P11 = P[4], P12 = P[5];
        float P20 = P[6], P21 = P[7], P22 = P[8];

        float* o = &s_out[tid * 9];
        o[0] = P00 * R00 + P01 * R10 + P02 * R20;
        o[1] = P00 * R01 + P01 * R11 + P02 * R21;
        o[2] = P00 * R02 + P01 * R12 + P02 * R22;
        o[3] = P10 * R00 + P11 * R10 + P12 * R20;
        o[4] = P10 * R01 + P11 * R11 + P12 * R21;
        o[5] = P10 * R02 + P11 * R12 + P12 * R22;
        o[6] = P20 * R00 + P21 * R10 + P22 * R20;
        o[7] = P20 * R01 + P21 * R11 + P22 * R21;
        o[8] = P20 * R02 + P21 * R12 + P22 * R22;
    }
    __syncthreads();

    {
        float4* dst = reinterpret_cast<float4*>(out + row0 * 9);
        const float4* src = reinterpret_cast<const float4*>(s_out);
        dst[tid]       = src[tid];
        dst[tid + 256] = src[tid + 256];
        if (tid < 64) dst[tid + 512] = src[tid + 512];
    }
}

// ---------------- Fallback: fused single kernel (generic) ----------------
__global__ void rexp_generic_kernel(
    const float* __restrict__ ybin, const float* __restrict__ yres,
    const float* __restrict__ key_poses, float* __restrict__ out,
    int B, int C)
{
    long long b = (long long)blockIdx.x * blockDim.x + threadIdx.x;
    if (b >= B) return;
    const float* row = ybin + b * C;
    float best = -INFINITY; int bi = 0;
    for (int j = 0; j < C; ++j) if (row[j] > best) { best = row[j]; bi = j; }
    float rx = yres[b*3], ry = yres[b*3+1], rz = yres[b*3+2];
    float angle = sqrtf(rx*rx + ry*ry + rz*rz);
    float inv = 1.0f / fmaxf(angle, 1e-12f);
    float ax = rx*inv, ay = ry*inv, az = rz*inv;
    float s, cosv; __sincosf(angle, &s, &cosv);
    float c = 1.0f - cosv;
    float axx=ax*ax, ayy=ay*ay, azz=az*az, axy=ax*ay, axz=ax*az, ayz=ay*az;
    float R00=1.0f+c*(-ayy-azz), R01=-s*az+c*axy, R02= s*ay+c*axz;
    float R10= s*az+c*axy, R11=1.0f+c*(-axx-azz), R12=-s*ax+c*ayz;
    float R20=-s*ay+c*axz, R21= s*ax+c*ayz, R22=1.0f+c*(-axx-ayy);
    const float* P = key_poses + bi * 9;
    float* o = out + b * 9;
    o[0]=P[0]*R00+P[1]*R10+P[2]*R20; o[1]=P[0]*R01+P[1]*R11+P[2]*R21; o[2]=P[0]*R02+P[1]*R12+P[2]*R22;
    o[3]=P[3]*R00+P[4]*R10+P[5]*R20; o[4]=P[3]*R01+P[4]*R11+P[5]*R21; o[5]=P[3]*R02+P[4]*R12+P[5]*R22;
    o[6]=P[6]*R00+P[7]*R10+P[8]*R20; o[7]=P[6]*R01+P[7]*R11+P[8]*R21; o[8]=P[6]*R02+P[7]*R12+P[8]*R22;
}

extern "C" void kernel_launch(void* const* d_in, const int* in_sizes, int n_in,
                              void* d_out, int out_size, void* d_ws, size_t ws_size,
                              hipStream_t stream) {
    const float* ybin      = (const float*)d_in[0];
    const float* yres      = (const float*)d_in[1];
    const float* key_poses = (const float*)d_in[2];
    float* out = (float*)d_out;

    int B = in_sizes[1] / 3;
    int C = in_sizes[0] / B;   // == 100 here

    if (C == 100 && (B % ROWS_PER_BLOCK) == 0 && ws_size >= (size_t)B) {
        unsigned char* idx = (unsigned char*)d_ws;
        int g1 = (B + 63) / 64;                  // 64 rows per 256-thread block
        argmax100_kernel<<<g1, 256, 0, stream>>>(ybin, idx, B);
        int g2 = B / ROWS_PER_BLOCK;
        apply_kernel<<<g2, 256, 0, stream>>>(idx, yres, key_poses, out);
    } else {
        rexp_generic_kernel<<<(B + 255) / 256, 256, 0, stream>>>(
            ybin, yres, key_poses, out, B, C);
    }
}